// Round 11
// baseline (254.405 us; speedup 1.0000x reference)
//
#include <hip/hip_runtime.h>
#include <hip/hip_bf16.h>

#define D 128
#define NEG_SLOPE 0.2f
#define SCAN_BS 512
#define RT 4   // row-tiles per wave in the dense GEMM kernels

typedef __attribute__((ext_vector_type(8))) short short8;
typedef __attribute__((ext_vector_type(4))) short short4v;
typedef __attribute__((ext_vector_type(4))) float f32x4;

__device__ __forceinline__ float group_max16(float v) {
#pragma unroll
    for (int m = 8; m >= 1; m >>= 1) v = fmaxf(v, __shfl_xor(v, m));
    return v;
}
__device__ __forceinline__ float group_sum16(float v) {
#pragma unroll
    for (int m = 8; m >= 1; m >>= 1) v += __shfl_xor(v, m);
    return v;
}

__device__ __forceinline__ unsigned short f2bfu(float f) {
    __hip_bfloat16 h = __float2bfloat16(f);
    return *reinterpret_cast<unsigned short*>(&h);
}

__device__ __forceinline__ float bf2f(unsigned short u) {
    return __uint_as_float(((unsigned)u) << 16);
}

__device__ __forceinline__ short8 load_bf8(const float* p) {
    float4 p0 = *(const float4*)p;
    float4 p1 = *(const float4*)(p + 4);
    short8 r;
    r[0] = (short)f2bfu(p0.x); r[1] = (short)f2bfu(p0.y);
    r[2] = (short)f2bfu(p0.z); r[3] = (short)f2bfu(p0.w);
    r[4] = (short)f2bfu(p1.x); r[5] = (short)f2bfu(p1.y);
    r[6] = (short)f2bfu(p1.z); r[7] = (short)f2bfu(p1.w);
    return r;
}

// transpose + convert the three 128x128 weight mats to bf16 (WT[n][k] = W[k][n])
__global__ void k_wt(const float* __restrict__ Wg, const float* __restrict__ Wl,
                     const float* __restrict__ Wr, short* __restrict__ WgT,
                     short* __restrict__ WlT, short* __restrict__ WrT) {
    int i = blockIdx.x * blockDim.x + threadIdx.x;
    int m = i >> 14;
    int r = (i >> 7) & 127;
    int c = i & 127;
    const float* src = (m == 0) ? Wg : (m == 1) ? Wl : Wr;
    short* dst = (m == 0) ? WgT : (m == 1) ? WlT : WrT;
    dst[r * D + c] = (short)f2bfu(src[c * D + r]);
}

// ---- CSR build ----
__global__ void k_hist(const int* __restrict__ ei, int* __restrict__ cnt, int E) {
    int i = blockIdx.x * blockDim.x + threadIdx.x;
    if (i < E) atomicAdd(&cnt[ei[E + i]], 1);
}

__global__ void k_scan_block(const int* __restrict__ cnt, int* __restrict__ incl,
                             int* __restrict__ btot, int N) {
    __shared__ int s[SCAN_BS];
    int t = threadIdx.x, i = blockIdx.x * SCAN_BS + t;
    int v = (i < N) ? cnt[i] : 0;
    s[t] = v;
    __syncthreads();
    for (int d = 1; d < SCAN_BS; d <<= 1) {
        int u = (t >= d) ? s[t - d] : 0;
        __syncthreads();
        s[t] += u;
        __syncthreads();
    }
    if (i < N) incl[i] = s[t];
    if (t == SCAN_BS - 1) btot[blockIdx.x] = s[t];
}

__global__ void k_scan_tot(int* __restrict__ btot, int nb) {
    __shared__ int s[1024];
    int t = threadIdx.x;
    int v = (t < nb) ? btot[t] : 0;
    s[t] = v;
    __syncthreads();
    for (int d = 1; d < 1024; d <<= 1) {
        int u = (t >= d) ? s[t - d] : 0;
        __syncthreads();
        s[t] += u;
        __syncthreads();
    }
    if (t < nb) btot[t] = s[t] - v;
}

__global__ void k_scan_add(const int* __restrict__ cnt, int* __restrict__ off,
                           const int* __restrict__ btot, int N) {
    int i = blockIdx.x * blockDim.x + threadIdx.x;
    if (i < N) off[i] = off[i] + btot[i / SCAN_BS] - cnt[i];
}

__global__ void k_bucket(const int* __restrict__ ei, const int* __restrict__ off,
                         int* __restrict__ fill, int* __restrict__ csr, int E) {
    int i = blockIdx.x * blockDim.x + threadIdx.x;
    if (i < E) {
        int dt = ei[E + i];
        int p = off[dt] + atomicAdd(&fill[dt], 1);
        csr[p] = ei[i];
    }
}

// ---- K1: h = x @ Wg — RT row-tiles/wave, weight reuse, swapped-operand MFMA ----
__global__ void k_gemm_h(const float* __restrict__ x, const short* __restrict__ WgT,
                         const float* __restrict__ att_src, const float* __restrict__ att_dst,
                         unsigned short* __restrict__ h_bf, float* __restrict__ a_src,
                         float* __restrict__ a_dst, int N) {
    const int lane = threadIdx.x & 63;
    const int wave = threadIdx.x >> 6;
    const int lrow = lane & 15, lgrp = lane >> 4;
    const int base = blockIdx.x * (64 * RT) + wave * (16 * RT);

    short8 ax[RT][4];
    int rows[RT];
    bool okr[RT];
#pragma unroll
    for (int t = 0; t < RT; ++t) {
        rows[t] = base + t * 16 + lrow;
        okr[t] = (rows[t] < N);
        const float* xr = x + (size_t)rows[t] * D + lgrp * 8;
#pragma unroll
        for (int kt = 0; kt < 4; ++kt) {
            if (okr[t]) ax[t][kt] = load_bf8(xr + kt * 32);
            else { short8 zf; for (int j = 0; j < 8; ++j) zf[j] = 0; ax[t][kt] = zf; }
        }
    }

    float ps[RT], pd[RT];
#pragma unroll
    for (int t = 0; t < RT; ++t) { ps[t] = 0.f; pd[t] = 0.f; }

#pragma unroll
    for (int f = 0; f < 8; ++f) {
        const short* wb = WgT + ((f * 16 + lrow) * D + lgrp * 8);
        short8 wgf[4];
#pragma unroll
        for (int kt = 0; kt < 4; ++kt) wgf[kt] = *(const short8*)(wb + kt * 32);
        const int cb = f * 16 + lgrp * 4;
        float as[4], adv[4];
#pragma unroll
        for (int j = 0; j < 4; ++j) { as[j] = att_src[cb + j]; adv[j] = att_dst[cb + j]; }
#pragma unroll
        for (int t = 0; t < RT; ++t) {
            f32x4 a = (f32x4){0.f, 0.f, 0.f, 0.f};
#pragma unroll
            for (int kt = 0; kt < 4; ++kt)
                a = __builtin_amdgcn_mfma_f32_16x16x32_bf16(wgf[kt], ax[t][kt], a, 0, 0, 0);
            short4v hv;
#pragma unroll
            for (int j = 0; j < 4; ++j) {
                float v = a[j];
                hv[j] = (short)f2bfu(v);
                ps[t] += v * as[j];
                pd[t] += v * adv[j];
            }
            if (okr[t]) *(short4v*)(h_bf + (size_t)rows[t] * D + cb) = hv;
        }
    }
#pragma unroll
    for (int t = 0; t < RT; ++t) {
        float s = ps[t], dd = pd[t];
        s += __shfl_xor(s, 16); s += __shfl_xor(s, 32);
        dd += __shfl_xor(dd, 16); dd += __shfl_xor(dd, 32);
        if (lgrp == 0 && okr[t]) { a_src[rows[t]] = s; a_dst[rows[t]] = dd; }
    }
}

// ---- GAT aggregation: 16 lanes per dst node (4 nodes/wave), 4-way MLP unroll ----
__global__ void k_attn(const int* __restrict__ csr, const int* __restrict__ off,
                       const int* __restrict__ cnt, const float* __restrict__ a_src,
                       const float* __restrict__ a_dst, const unsigned short* __restrict__ h_bf,
                       const float* __restrict__ bg, unsigned short* __restrict__ hg_bf, int N) {
    const int lane = threadIdx.x & 63;
    const int l16 = lane & 15, grp = lane >> 4;
    const int gbase = grp << 4;
    const int d = blockIdx.x * 16 + ((threadIdx.x >> 6) << 2) + grp;
    if (d >= N) return;
    const int deg = cnt[d], o = off[d];
    const float ad = a_dst[d];
    float es = a_src[d] + ad;
    es = (es > 0.f) ? es : NEG_SLOPE * es;

    const int fo = l16 * 8;
    short8 hv = *(const short8*)(h_bf + (size_t)d * D + fo);
    float acc[8];
    float inv;

    if (deg <= 16) {
        int sv = 0;
        float e = -INFINITY;
        if (l16 < deg) {
            sv = csr[o + l16];
            float t = a_src[sv] + ad;
            e = (t > 0.f) ? t : NEG_SLOPE * t;
        }
        float mx = fmaxf(group_max16(e), es);
        float p = (l16 < deg) ? expf(e - mx) : 0.f;
        float pself = expf(es - mx);
        inv = 1.f / (group_sum16(p) + pself);
#pragma unroll
        for (int j = 0; j < 8; ++j) acc[j] = pself * bf2f((unsigned short)hv[j]);
        int i = 0;
        for (; i + 4 <= deg; i += 4) {
            int s0 = __shfl(sv, gbase + i);
            int s1 = __shfl(sv, gbase + i + 1);
            int s2 = __shfl(sv, gbase + i + 2);
            int s3 = __shfl(sv, gbase + i + 3);
            float p0 = __shfl(p, gbase + i);
            float p1 = __shfl(p, gbase + i + 1);
            float p2 = __shfl(p, gbase + i + 2);
            float p3 = __shfl(p, gbase + i + 3);
            short8 r0 = *(const short8*)(h_bf + (size_t)s0 * D + fo);
            short8 r1 = *(const short8*)(h_bf + (size_t)s1 * D + fo);
            short8 r2 = *(const short8*)(h_bf + (size_t)s2 * D + fo);
            short8 r3 = *(const short8*)(h_bf + (size_t)s3 * D + fo);
#pragma unroll
            for (int j = 0; j < 8; ++j)
                acc[j] += p0 * bf2f((unsigned short)r0[j]) + p1 * bf2f((unsigned short)r1[j])
                        + p2 * bf2f((unsigned short)r2[j]) + p3 * bf2f((unsigned short)r3[j]);
        }
        for (; i < deg; ++i) {
            int s = __shfl(sv, gbase + i);
            float pi = __shfl(p, gbase + i);
            short8 row = *(const short8*)(h_bf + (size_t)s * D + fo);
#pragma unroll
            for (int j = 0; j < 8; ++j) acc[j] += pi * bf2f((unsigned short)row[j]);
        }
    } else {  // rare fallback
        float m2 = es;
        for (int i = l16; i < deg; i += 16) {
            float t = a_src[csr[o + i]] + ad;
            t = (t > 0.f) ? t : NEG_SLOPE * t;
            m2 = fmaxf(m2, t);
        }
        float mx = group_max16(m2);
        float zp = 0.f;
        for (int i = l16; i < deg; i += 16) {
            float t = a_src[csr[o + i]] + ad;
            t = (t > 0.f) ? t : NEG_SLOPE * t;
            zp += expf(t - mx);
        }
        float pself = expf(es - mx);
        inv = 1.f / (group_sum16(zp) + pself);
#pragma unroll
        for (int j = 0; j < 8; ++j) acc[j] = pself * bf2f((unsigned short)hv[j]);
        for (int i = 0; i < deg; ++i) {
            int s = csr[o + i];
            float t = a_src[s] + ad;
            t = (t > 0.f) ? t : NEG_SLOPE * t;
            float pi = expf(t - mx);
            short8 row = *(const short8*)(h_bf + (size_t)s * D + fo);
#pragma unroll
            for (int j = 0; j < 8; ++j) acc[j] += pi * bf2f((unsigned short)row[j]);
        }
    }
    short8 r;
#pragma unroll
    for (int j = 0; j < 8; ++j) r[j] = (short)f2bfu(acc[j] * inv + bg[fo + j]);
    *(short8*)(hg_bf + (size_t)d * D + fo) = r;
}

// ---- K3: hgWl = bf16(hg@Wl); hgWr = bf16(hg@Wr) — RT row-tiles/wave, weight reuse ----
__global__ void k_gemm2(const unsigned short* __restrict__ hg_bf,
                        const short* __restrict__ WlT, const short* __restrict__ WrT,
                        unsigned short* __restrict__ hgWl_bf,
                        unsigned short* __restrict__ hgWr_bf, int N) {
    const int lane = threadIdx.x & 63;
    const int wave = threadIdx.x >> 6;
    const int lrow = lane & 15, lgrp = lane >> 4;
    const int base = blockIdx.x * (64 * RT) + wave * (16 * RT);

    short8 ah[RT][4];
    int rows[RT];
    bool okr[RT];
#pragma unroll
    for (int t = 0; t < RT; ++t) {
        rows[t] = base + t * 16 + lrow;
        okr[t] = (rows[t] < N);
        const unsigned short* hp = hg_bf + (size_t)rows[t] * D + lgrp * 8;
#pragma unroll
        for (int kt = 0; kt < 4; ++kt) {
            if (okr[t]) ah[t][kt] = *(const short8*)(hp + kt * 32);
            else { short8 zf; for (int j = 0; j < 8; ++j) zf[j] = 0; ah[t][kt] = zf; }
        }
    }

#pragma unroll
    for (int f = 0; f < 8; ++f) {
        const short* wl = WlT + ((f * 16 + lrow) * D + lgrp * 8);
        const short* wr = WrT + ((f * 16 + lrow) * D + lgrp * 8);
        short8 wlf[4], wrf[4];
#pragma unroll
        for (int kt = 0; kt < 4; ++kt) {
            wlf[kt] = *(const short8*)(wl + kt * 32);
            wrf[kt] = *(const short8*)(wr + kt * 32);
        }
        const int cb = f * 16 + lgrp * 4;
#pragma unroll
        for (int t = 0; t < RT; ++t) {
            f32x4 aL = (f32x4){0.f, 0.f, 0.f, 0.f};
            f32x4 aR = (f32x4){0.f, 0.f, 0.f, 0.f};
#pragma unroll
            for (int kt = 0; kt < 4; ++kt) {
                aL = __builtin_amdgcn_mfma_f32_16x16x32_bf16(wlf[kt], ah[t][kt], aL, 0, 0, 0);
                aR = __builtin_amdgcn_mfma_f32_16x16x32_bf16(wrf[kt], ah[t][kt], aR, 0, 0, 0);
            }
            if (okr[t]) {
                short4v vl, vr;
#pragma unroll
                for (int j = 0; j < 4; ++j) {
                    vl[j] = (short)f2bfu(aL[j]);
                    vr[j] = (short)f2bfu(aR[j]);
                }
                *(short4v*)(hgWl_bf + (size_t)rows[t] * D + cb) = vl;
                *(short4v*)(hgWr_bf + (size_t)rows[t] * D + cb) = vr;
            }
        }
    }
}

// ---- K4: out = normalize(mean-gather(hgWl) + hgWr + bl) — pure gather ----
__global__ void k_final(const int* __restrict__ csr, const int* __restrict__ off,
                        const int* __restrict__ cnt, const unsigned short* __restrict__ hgWl_bf,
                        const unsigned short* __restrict__ hgWr_bf, const float* __restrict__ bl,
                        float* __restrict__ out, int N) {
    const int lane = threadIdx.x & 63;
    const int l16 = lane & 15, grp = lane >> 4;
    const int gbase = grp << 4;
    const int d = blockIdx.x * 16 + ((threadIdx.x >> 6) << 2) + grp;
    if (d >= N) return;
    const int deg = cnt[d], o = off[d];
    const int fo = l16 * 8;

    short8 wrow = *(const short8*)(hgWr_bf + (size_t)d * D + fo);
    float4 b0 = *(const float4*)(bl + fo);
    float4 b1 = *(const float4*)(bl + fo + 4);

    float acc[8];
#pragma unroll
    for (int j = 0; j < 8; ++j) acc[j] = 0.f;

    if (deg <= 16) {
        int sv = 0;
        if (l16 < deg) sv = csr[o + l16];
        int i = 0;
        for (; i + 4 <= deg; i += 4) {
            int s0 = __shfl(sv, gbase + i);
            int s1 = __shfl(sv, gbase + i + 1);
            int s2 = __shfl(sv, gbase + i + 2);
            int s3 = __shfl(sv, gbase + i + 3);
            short8 r0 = *(const short8*)(hgWl_bf + (size_t)s0 * D + fo);
            short8 r1 = *(const short8*)(hgWl_bf + (size_t)s1 * D + fo);
            short8 r2 = *(const short8*)(hgWl_bf + (size_t)s2 * D + fo);
            short8 r3 = *(const short8*)(hgWl_bf + (size_t)s3 * D + fo);
#pragma unroll
            for (int j = 0; j < 8; ++j)
                acc[j] += bf2f((unsigned short)r0[j]) + bf2f((unsigned short)r1[j])
                        + bf2f((unsigned short)r2[j]) + bf2f((unsigned short)r3[j]);
        }
        for (; i < deg; ++i) {
            int s = __shfl(sv, gbase + i);
            short8 row = *(const short8*)(hgWl_bf + (size_t)s * D + fo);
#pragma unroll
            for (int j = 0; j < 8; ++j) acc[j] += bf2f((unsigned short)row[j]);
        }
    } else {
        for (int i = 0; i < deg; ++i) {
            int s = csr[o + i];
            short8 row = *(const short8*)(hgWl_bf + (size_t)s * D + fo);
#pragma unroll
            for (int j = 0; j < 8; ++j) acc[j] += bf2f((unsigned short)row[j]);
        }
    }

    const float minv = 1.f / fmaxf((float)deg, 1.f);
    float v[8];
    v[0] = acc[0] * minv + bf2f((unsigned short)wrow[0]) + b0.x;
    v[1] = acc[1] * minv + bf2f((unsigned short)wrow[1]) + b0.y;
    v[2] = acc[2] * minv + bf2f((unsigned short)wrow[2]) + b0.z;
    v[3] = acc[3] * minv + bf2f((unsigned short)wrow[3]) + b0.w;
    v[4] = acc[4] * minv + bf2f((unsigned short)wrow[4]) + b1.x;
    v[5] = acc[5] * minv + bf2f((unsigned short)wrow[5]) + b1.y;
    v[6] = acc[6] * minv + bf2f((unsigned short)wrow[6]) + b1.z;
    v[7] = acc[7] * minv + bf2f((unsigned short)wrow[7]) + b1.w;
    float ss = 0.f;
#pragma unroll
    for (int j = 0; j < 8; ++j) ss += v[j] * v[j];
    ss = group_sum16(ss);
    float sc = 1.f / fmaxf(sqrtf(ss), 1e-12f);
    float* orow = out + (size_t)d * D + fo;
    float4 w0 = {v[0] * sc, v[1] * sc, v[2] * sc, v[3] * sc};
    float4 w1 = {v[4] * sc, v[5] * sc, v[6] * sc, v[7] * sc};
    *(float4*)orow = w0;
    *(float4*)(orow + 4) = w1;
}

extern "C" void kernel_launch(void* const* d_in, const int* in_sizes, int n_in,
                              void* d_out, int out_size, void* d_ws, size_t ws_size,
                              hipStream_t stream) {
    const float* x       = (const float*)d_in[0];
    const int*   ei      = (const int*)d_in[1];
    const float* Wg      = (const float*)d_in[2];
    const float* att_src = (const float*)d_in[3];
    const float* att_dst = (const float*)d_in[4];
    const float* bg      = (const float*)d_in[5];
    const float* Wl      = (const float*)d_in[6];
    const float* bl      = (const float*)d_in[7];
    const float* Wr      = (const float*)d_in[8];
    const int N = in_sizes[0] / D;
    const int E = in_sizes[1] / 2;

    char* w = (char*)d_ws;
    unsigned short* h_bf    = (unsigned short*)w;  w += (size_t)N * D * 2;
    unsigned short* hg_bf   = (unsigned short*)w;  w += (size_t)N * D * 2;
    unsigned short* hgWl_bf = (unsigned short*)w;  w += (size_t)N * D * 2;
    unsigned short* hgWr_bf = (unsigned short*)w;  w += (size_t)N * D * 2;
    float* a_src = (float*)w;  w += (size_t)N * 4;
    float* a_dst = (float*)w;  w += (size_t)N * 4;
    int*   cnt_i = (int*)w;    w += (size_t)N * 4;
    int*   off   = (int*)w;    w += (size_t)N * 4;
    int*   fill  = (int*)w;    w += (size_t)N * 4;
    int*   btot  = (int*)w;    w += 1024 * 4;
    int*   csr   = (int*)w;    w += (size_t)E * 4;
    short* WgT   = (short*)w;  w += (size_t)D * D * 2;
    short* WlT   = (short*)w;  w += (size_t)D * D * 2;
    short* WrT   = (short*)w;  w += (size_t)D * D * 2;
    float* out_f = (float*)d_out;

    (void)hipMemsetAsync(cnt_i, 0, (size_t)N * 4, stream);
    (void)hipMemsetAsync(fill, 0, (size_t)N * 4, stream);

    const int nb = (N + SCAN_BS - 1) / SCAN_BS;

    k_wt<<<(3 * D * D) / 256, 256, 0, stream>>>(Wg, Wl, Wr, WgT, WlT, WrT);
    k_hist<<<(E + 255) / 256, 256, 0, stream>>>(ei, cnt_i, E);
    k_scan_block<<<nb, SCAN_BS, 0, stream>>>(cnt_i, off, btot, N);
    k_scan_tot<<<1, 1024, 0, stream>>>(btot, nb);
    k_scan_add<<<(N + 255) / 256, 256, 0, stream>>>(cnt_i, off, btot, N);
    k_bucket<<<(E + 255) / 256, 256, 0, stream>>>(ei, off, fill, csr, E);

    k_gemm_h<<<(N + 64 * RT - 1) / (64 * RT), 256, 0, stream>>>(x, WgT, att_src, att_dst, h_bf, a_src, a_dst, N);
    k_attn<<<(N + 15) / 16, 256, 0, stream>>>(csr, off, cnt_i, a_src, a_dst, h_bf, bg, hg_bf, N);
    k_gemm2<<<(N + 64 * RT - 1) / (64 * RT), 256, 0, stream>>>(hg_bf, WlT, WrT, hgWl_bf, hgWr_bf, N);
    k_final<<<(N + 15) / 16, 256, 0, stream>>>(csr, off, cnt_i, hgWl_bf, hgWr_bf, bl, out_f, N);
}

// Round 12
// 211.466 us; speedup vs baseline: 1.2031x; 1.2031x over previous
//
#include <hip/hip_runtime.h>
#include <hip/hip_bf16.h>

#define D 128
#define NEG_SLOPE 0.2f
#define SCAN_BS 512
#define RT 4   // row-tiles per wave in the dense GEMM kernels

typedef __attribute__((ext_vector_type(8))) short short8;
typedef __attribute__((ext_vector_type(4))) short short4v;
typedef __attribute__((ext_vector_type(4))) float f32x4;

__device__ __forceinline__ float group_max16(float v) {
#pragma unroll
    for (int m = 8; m >= 1; m >>= 1) v = fmaxf(v, __shfl_xor(v, m));
    return v;
}
__device__ __forceinline__ float group_sum16(float v) {
#pragma unroll
    for (int m = 8; m >= 1; m >>= 1) v += __shfl_xor(v, m);
    return v;
}

__device__ __forceinline__ unsigned short f2bfu(float f) {
    __hip_bfloat16 h = __float2bfloat16(f);
    return *reinterpret_cast<unsigned short*>(&h);
}

__device__ __forceinline__ float bf2f(unsigned short u) {
    return __uint_as_float(((unsigned)u) << 16);
}

__device__ __forceinline__ short8 load_bf8(const float* p) {
    float4 p0 = *(const float4*)p;
    float4 p1 = *(const float4*)(p + 4);
    short8 r;
    r[0] = (short)f2bfu(p0.x); r[1] = (short)f2bfu(p0.y);
    r[2] = (short)f2bfu(p0.z); r[3] = (short)f2bfu(p0.w);
    r[4] = (short)f2bfu(p1.x); r[5] = (short)f2bfu(p1.y);
    r[6] = (short)f2bfu(p1.z); r[7] = (short)f2bfu(p1.w);
    return r;
}

// transpose + convert the three 128x128 weight mats to bf16 (WT[n][k] = W[k][n])
__global__ void k_wt(const float* __restrict__ Wg, const float* __restrict__ Wl,
                     const float* __restrict__ Wr, short* __restrict__ WgT,
                     short* __restrict__ WlT, short* __restrict__ WrT) {
    int i = blockIdx.x * blockDim.x + threadIdx.x;
    int m = i >> 14;
    int r = (i >> 7) & 127;
    int c = i & 127;
    const float* src = (m == 0) ? Wg : (m == 1) ? Wl : Wr;
    short* dst = (m == 0) ? WgT : (m == 1) ? WlT : WrT;
    dst[r * D + c] = (short)f2bfu(src[c * D + r]);
}

// ---- CSR build ----
__global__ void k_hist(const int* __restrict__ ei, int* __restrict__ cnt, int E) {
    int i = blockIdx.x * blockDim.x + threadIdx.x;
    if (i < E) atomicAdd(&cnt[ei[E + i]], 1);
}

__global__ void k_scan_block(const int* __restrict__ cnt, int* __restrict__ incl,
                             int* __restrict__ btot, int N) {
    __shared__ int s[SCAN_BS];
    int t = threadIdx.x, i = blockIdx.x * SCAN_BS + t;
    int v = (i < N) ? cnt[i] : 0;
    s[t] = v;
    __syncthreads();
    for (int d = 1; d < SCAN_BS; d <<= 1) {
        int u = (t >= d) ? s[t - d] : 0;
        __syncthreads();
        s[t] += u;
        __syncthreads();
    }
    if (i < N) incl[i] = s[t];
    if (t == SCAN_BS - 1) btot[blockIdx.x] = s[t];
}

__global__ void k_scan_tot(int* __restrict__ btot, int nb) {
    __shared__ int s[1024];
    int t = threadIdx.x;
    int v = (t < nb) ? btot[t] : 0;
    s[t] = v;
    __syncthreads();
    for (int d = 1; d < 1024; d <<= 1) {
        int u = (t >= d) ? s[t - d] : 0;
        __syncthreads();
        s[t] += u;
        __syncthreads();
    }
    if (t < nb) btot[t] = s[t] - v;
}

__global__ void k_scan_add(const int* __restrict__ cnt, int* __restrict__ off,
                           const int* __restrict__ btot, int N) {
    int i = blockIdx.x * blockDim.x + threadIdx.x;
    if (i < N) off[i] = off[i] + btot[i / SCAN_BS] - cnt[i];
}

__global__ void k_bucket(const int* __restrict__ ei, const int* __restrict__ off,
                         int* __restrict__ fill, int* __restrict__ csr, int E) {
    int i = blockIdx.x * blockDim.x + threadIdx.x;
    if (i < E) {
        int dt = ei[E + i];
        int p = off[dt] + atomicAdd(&fill[dt], 1);
        csr[p] = ei[i];
    }
}

// ---- K1: h = x @ Wg — RT row-tiles/wave, weight reuse, swapped-operand MFMA ----
// __launch_bounds__(256,1): allow full VGPR budget so RT fragments stay resident (r11 spilled at default cap)
__global__ void __launch_bounds__(256, 1)
k_gemm_h(const float* __restrict__ x, const short* __restrict__ WgT,
         const float* __restrict__ att_src, const float* __restrict__ att_dst,
         unsigned short* __restrict__ h_bf, float* __restrict__ a_src,
         float* __restrict__ a_dst, int N) {
    const int lane = threadIdx.x & 63;
    const int wave = threadIdx.x >> 6;
    const int lrow = lane & 15, lgrp = lane >> 4;
    const int base = blockIdx.x * (64 * RT) + wave * (16 * RT);

    short8 ax[RT][4];
    int rows[RT];
    bool okr[RT];
#pragma unroll
    for (int t = 0; t < RT; ++t) {
        rows[t] = base + t * 16 + lrow;
        okr[t] = (rows[t] < N);
        const float* xr = x + (size_t)rows[t] * D + lgrp * 8;
#pragma unroll
        for (int kt = 0; kt < 4; ++kt) {
            if (okr[t]) ax[t][kt] = load_bf8(xr + kt * 32);
            else { short8 zf; for (int j = 0; j < 8; ++j) zf[j] = 0; ax[t][kt] = zf; }
        }
    }

    float ps[RT], pd[RT];
#pragma unroll
    for (int t = 0; t < RT; ++t) { ps[t] = 0.f; pd[t] = 0.f; }

#pragma unroll
    for (int f = 0; f < 8; ++f) {
        const short* wb = WgT + ((f * 16 + lrow) * D + lgrp * 8);
        short8 wgf[4];
#pragma unroll
        for (int kt = 0; kt < 4; ++kt) wgf[kt] = *(const short8*)(wb + kt * 32);
        const int cb = f * 16 + lgrp * 4;
        float as[4], adv[4];
#pragma unroll
        for (int j = 0; j < 4; ++j) { as[j] = att_src[cb + j]; adv[j] = att_dst[cb + j]; }
#pragma unroll
        for (int t = 0; t < RT; ++t) {
            f32x4 a = (f32x4){0.f, 0.f, 0.f, 0.f};
#pragma unroll
            for (int kt = 0; kt < 4; ++kt)
                a = __builtin_amdgcn_mfma_f32_16x16x32_bf16(wgf[kt], ax[t][kt], a, 0, 0, 0);
            short4v hv;
#pragma unroll
            for (int j = 0; j < 4; ++j) {
                float v = a[j];
                hv[j] = (short)f2bfu(v);
                ps[t] += v * as[j];
                pd[t] += v * adv[j];
            }
            if (okr[t]) *(short4v*)(h_bf + (size_t)rows[t] * D + cb) = hv;
        }
    }
#pragma unroll
    for (int t = 0; t < RT; ++t) {
        float s = ps[t], dd = pd[t];
        s += __shfl_xor(s, 16); s += __shfl_xor(s, 32);
        dd += __shfl_xor(dd, 16); dd += __shfl_xor(dd, 32);
        if (lgrp == 0 && okr[t]) { a_src[rows[t]] = s; a_dst[rows[t]] = dd; }
    }
}

// ---- GAT aggregation: 16 lanes per dst node (4 nodes/wave), 4-way MLP unroll ----
__global__ void k_attn(const int* __restrict__ csr, const int* __restrict__ off,
                       const int* __restrict__ cnt, const float* __restrict__ a_src,
                       const float* __restrict__ a_dst, const unsigned short* __restrict__ h_bf,
                       const float* __restrict__ bg, unsigned short* __restrict__ hg_bf, int N) {
    const int lane = threadIdx.x & 63;
    const int l16 = lane & 15, grp = lane >> 4;
    const int gbase = grp << 4;
    const int d = blockIdx.x * 16 + ((threadIdx.x >> 6) << 2) + grp;
    if (d >= N) return;
    const int deg = cnt[d], o = off[d];
    const float ad = a_dst[d];
    float es = a_src[d] + ad;
    es = (es > 0.f) ? es : NEG_SLOPE * es;

    const int fo = l16 * 8;
    short8 hv = *(const short8*)(h_bf + (size_t)d * D + fo);
    float acc[8];
    float inv;

    if (deg <= 16) {
        int sv = 0;
        float e = -INFINITY;
        if (l16 < deg) {
            sv = csr[o + l16];
            float t = a_src[sv] + ad;
            e = (t > 0.f) ? t : NEG_SLOPE * t;
        }
        float mx = fmaxf(group_max16(e), es);
        float p = (l16 < deg) ? expf(e - mx) : 0.f;
        float pself = expf(es - mx);
        inv = 1.f / (group_sum16(p) + pself);
#pragma unroll
        for (int j = 0; j < 8; ++j) acc[j] = pself * bf2f((unsigned short)hv[j]);
        int i = 0;
        for (; i + 4 <= deg; i += 4) {
            int s0 = __shfl(sv, gbase + i);
            int s1 = __shfl(sv, gbase + i + 1);
            int s2 = __shfl(sv, gbase + i + 2);
            int s3 = __shfl(sv, gbase + i + 3);
            float p0 = __shfl(p, gbase + i);
            float p1 = __shfl(p, gbase + i + 1);
            float p2 = __shfl(p, gbase + i + 2);
            float p3 = __shfl(p, gbase + i + 3);
            short8 r0 = *(const short8*)(h_bf + (size_t)s0 * D + fo);
            short8 r1 = *(const short8*)(h_bf + (size_t)s1 * D + fo);
            short8 r2 = *(const short8*)(h_bf + (size_t)s2 * D + fo);
            short8 r3 = *(const short8*)(h_bf + (size_t)s3 * D + fo);
#pragma unroll
            for (int j = 0; j < 8; ++j)
                acc[j] += p0 * bf2f((unsigned short)r0[j]) + p1 * bf2f((unsigned short)r1[j])
                        + p2 * bf2f((unsigned short)r2[j]) + p3 * bf2f((unsigned short)r3[j]);
        }
        for (; i < deg; ++i) {
            int s = __shfl(sv, gbase + i);
            float pi = __shfl(p, gbase + i);
            short8 row = *(const short8*)(h_bf + (size_t)s * D + fo);
#pragma unroll
            for (int j = 0; j < 8; ++j) acc[j] += pi * bf2f((unsigned short)row[j]);
        }
    } else {  // rare fallback
        float m2 = es;
        for (int i = l16; i < deg; i += 16) {
            float t = a_src[csr[o + i]] + ad;
            t = (t > 0.f) ? t : NEG_SLOPE * t;
            m2 = fmaxf(m2, t);
        }
        float mx = group_max16(m2);
        float zp = 0.f;
        for (int i = l16; i < deg; i += 16) {
            float t = a_src[csr[o + i]] + ad;
            t = (t > 0.f) ? t : NEG_SLOPE * t;
            zp += expf(t - mx);
        }
        float pself = expf(es - mx);
        inv = 1.f / (group_sum16(zp) + pself);
#pragma unroll
        for (int j = 0; j < 8; ++j) acc[j] = pself * bf2f((unsigned short)hv[j]);
        for (int i = 0; i < deg; ++i) {
            int s = csr[o + i];
            float t = a_src[s] + ad;
            t = (t > 0.f) ? t : NEG_SLOPE * t;
            float pi = expf(t - mx);
            short8 row = *(const short8*)(h_bf + (size_t)s * D + fo);
#pragma unroll
            for (int j = 0; j < 8; ++j) acc[j] += pi * bf2f((unsigned short)row[j]);
        }
    }
    short8 r;
#pragma unroll
    for (int j = 0; j < 8; ++j) r[j] = (short)f2bfu(acc[j] * inv + bg[fo + j]);
    *(short8*)(hg_bf + (size_t)d * D + fo) = r;
}

// ---- K3: hgWl = bf16(hg@Wl); hgWr = bf16(hg@Wr) — RT row-tiles/wave, weight reuse ----
__global__ void k_gemm2(const unsigned short* __restrict__ hg_bf,
                        const short* __restrict__ WlT, const short* __restrict__ WrT,
                        unsigned short* __restrict__ hgWl_bf,
                        unsigned short* __restrict__ hgWr_bf, int N) {
    const int lane = threadIdx.x & 63;
    const int wave = threadIdx.x >> 6;
    const int lrow = lane & 15, lgrp = lane >> 4;
    const int base = blockIdx.x * (64 * RT) + wave * (16 * RT);

    short8 ah[RT][4];
    int rows[RT];
    bool okr[RT];
#pragma unroll
    for (int t = 0; t < RT; ++t) {
        rows[t] = base + t * 16 + lrow;
        okr[t] = (rows[t] < N);
        const unsigned short* hp = hg_bf + (size_t)rows[t] * D + lgrp * 8;
#pragma unroll
        for (int kt = 0; kt < 4; ++kt) {
            if (okr[t]) ah[t][kt] = *(const short8*)(hp + kt * 32);
            else { short8 zf; for (int j = 0; j < 8; ++j) zf[j] = 0; ah[t][kt] = zf; }
        }
    }

#pragma unroll
    for (int f = 0; f < 8; ++f) {
        const short* wl = WlT + ((f * 16 + lrow) * D + lgrp * 8);
        const short* wr = WrT + ((f * 16 + lrow) * D + lgrp * 8);
        short8 wlf[4], wrf[4];
#pragma unroll
        for (int kt = 0; kt < 4; ++kt) {
            wlf[kt] = *(const short8*)(wl + kt * 32);
            wrf[kt] = *(const short8*)(wr + kt * 32);
        }
        const int cb = f * 16 + lgrp * 4;
#pragma unroll
        for (int t = 0; t < RT; ++t) {
            f32x4 aL = (f32x4){0.f, 0.f, 0.f, 0.f};
            f32x4 aR = (f32x4){0.f, 0.f, 0.f, 0.f};
#pragma unroll
            for (int kt = 0; kt < 4; ++kt) {
                aL = __builtin_amdgcn_mfma_f32_16x16x32_bf16(wlf[kt], ah[t][kt], aL, 0, 0, 0);
                aR = __builtin_amdgcn_mfma_f32_16x16x32_bf16(wrf[kt], ah[t][kt], aR, 0, 0, 0);
            }
            if (okr[t]) {
                short4v vl, vr;
#pragma unroll
                for (int j = 0; j < 4; ++j) {
                    vl[j] = (short)f2bfu(aL[j]);
                    vr[j] = (short)f2bfu(aR[j]);
                }
                *(short4v*)(hgWl_bf + (size_t)rows[t] * D + cb) = vl;
                *(short4v*)(hgWr_bf + (size_t)rows[t] * D + cb) = vr;
            }
        }
    }
}

// ---- K4: out = normalize(mean-gather(hgWl) + hgWr + bl) — pure gather ----
__global__ void k_final(const int* __restrict__ csr, const int* __restrict__ off,
                        const int* __restrict__ cnt, const unsigned short* __restrict__ hgWl_bf,
                        const unsigned short* __restrict__ hgWr_bf, const float* __restrict__ bl,
                        float* __restrict__ out, int N) {
    const int lane = threadIdx.x & 63;
    const int l16 = lane & 15, grp = lane >> 4;
    const int gbase = grp << 4;
    const int d = blockIdx.x * 16 + ((threadIdx.x >> 6) << 2) + grp;
    if (d >= N) return;
    const int deg = cnt[d], o = off[d];
    const int fo = l16 * 8;

    short8 wrow = *(const short8*)(hgWr_bf + (size_t)d * D + fo);
    float4 b0 = *(const float4*)(bl + fo);
    float4 b1 = *(const float4*)(bl + fo + 4);

    float acc[8];
#pragma unroll
    for (int j = 0; j < 8; ++j) acc[j] = 0.f;

    if (deg <= 16) {
        int sv = 0;
        if (l16 < deg) sv = csr[o + l16];
        int i = 0;
        for (; i + 4 <= deg; i += 4) {
            int s0 = __shfl(sv, gbase + i);
            int s1 = __shfl(sv, gbase + i + 1);
            int s2 = __shfl(sv, gbase + i + 2);
            int s3 = __shfl(sv, gbase + i + 3);
            short8 r0 = *(const short8*)(hgWl_bf + (size_t)s0 * D + fo);
            short8 r1 = *(const short8*)(hgWl_bf + (size_t)s1 * D + fo);
            short8 r2 = *(const short8*)(hgWl_bf + (size_t)s2 * D + fo);
            short8 r3 = *(const short8*)(hgWl_bf + (size_t)s3 * D + fo);
#pragma unroll
            for (int j = 0; j < 8; ++j)
                acc[j] += bf2f((unsigned short)r0[j]) + bf2f((unsigned short)r1[j])
                        + bf2f((unsigned short)r2[j]) + bf2f((unsigned short)r3[j]);
        }
        for (; i < deg; ++i) {
            int s = __shfl(sv, gbase + i);
            short8 row = *(const short8*)(hgWl_bf + (size_t)s * D + fo);
#pragma unroll
            for (int j = 0; j < 8; ++j) acc[j] += bf2f((unsigned short)row[j]);
        }
    } else {
        for (int i = 0; i < deg; ++i) {
            int s = csr[o + i];
            short8 row = *(const short8*)(hgWl_bf + (size_t)s * D + fo);
#pragma unroll
            for (int j = 0; j < 8; ++j) acc[j] += bf2f((unsigned short)row[j]);
        }
    }

    const float minv = 1.f / fmaxf((float)deg, 1.f);
    float v[8];
    v[0] = acc[0] * minv + bf2f((unsigned short)wrow[0]) + b0.x;
    v[1] = acc[1] * minv + bf2f((unsigned short)wrow[1]) + b0.y;
    v[2] = acc[2] * minv + bf2f((unsigned short)wrow[2]) + b0.z;
    v[3] = acc[3] * minv + bf2f((unsigned short)wrow[3]) + b0.w;
    v[4] = acc[4] * minv + bf2f((unsigned short)wrow[4]) + b1.x;
    v[5] = acc[5] * minv + bf2f((unsigned short)wrow[5]) + b1.y;
    v[6] = acc[6] * minv + bf2f((unsigned short)wrow[6]) + b1.z;
    v[7] = acc[7] * minv + bf2f((unsigned short)wrow[7]) + b1.w;
    float ss = 0.f;
#pragma unroll
    for (int j = 0; j < 8; ++j) ss += v[j] * v[j];
    ss = group_sum16(ss);
    float sc = 1.f / fmaxf(sqrtf(ss), 1e-12f);
    float* orow = out + (size_t)d * D + fo;
    float4 w0 = {v[0] * sc, v[1] * sc, v[2] * sc, v[3] * sc};
    float4 w1 = {v[4] * sc, v[5] * sc, v[6] * sc, v[7] * sc};
    *(float4*)orow = w0;
    *(float4*)(orow + 4) = w1;
}

extern "C" void kernel_launch(void* const* d_in, const int* in_sizes, int n_in,
                              void* d_out, int out_size, void* d_ws, size_t ws_size,
                              hipStream_t stream) {
    const float* x       = (const float*)d_in[0];
    const int*   ei      = (const int*)d_in[1];
    const float* Wg      = (const float*)d_in[2];
    const float* att_src = (const float*)d_in[3];
    const float* att_dst = (const float*)d_in[4];
    const float* bg      = (const float*)d_in[5];
    const float* Wl      = (const float*)d_in[6];
    const float* bl      = (const float*)d_in[7];
    const float* Wr      = (const float*)d_in[8];
    const int N = in_sizes[0] / D;
    const int E = in_sizes[1] / 2;

    char* w = (char*)d_ws;
    unsigned short* h_bf    = (unsigned short*)w;  w += (size_t)N * D * 2;
    unsigned short* hg_bf   = (unsigned short*)w;  w += (size_t)N * D * 2;
    unsigned short* hgWl_bf = (unsigned short*)w;  w += (size_t)N * D * 2;
    unsigned short* hgWr_bf = (unsigned short*)w;  w += (size_t)N * D * 2;
    float* a_src = (float*)w;  w += (size_t)N * 4;
    float* a_dst = (float*)w;  w += (size_t)N * 4;
    int*   cnt_i = (int*)w;    w += (size_t)N * 4;
    int*   off   = (int*)w;    w += (size_t)N * 4;
    int*   fill  = (int*)w;    w += (size_t)N * 4;
    int*   btot  = (int*)w;    w += 1024 * 4;
    int*   csr   = (int*)w;    w += (size_t)E * 4;
    short* WgT   = (short*)w;  w += (size_t)D * D * 2;
    short* WlT   = (short*)w;  w += (size_t)D * D * 2;
    short* WrT   = (short*)w;  w += (size_t)D * D * 2;
    float* out_f = (float*)d_out;

    (void)hipMemsetAsync(cnt_i, 0, (size_t)N * 4, stream);
    (void)hipMemsetAsync(fill, 0, (size_t)N * 4, stream);

    const int nb = (N + SCAN_BS - 1) / SCAN_BS;

    k_wt<<<(3 * D * D) / 256, 256, 0, stream>>>(Wg, Wl, Wr, WgT, WlT, WrT);
    k_hist<<<(E + 255) / 256, 256, 0, stream>>>(ei, cnt_i, E);
    k_scan_block<<<nb, SCAN_BS, 0, stream>>>(cnt_i, off, btot, N);
    k_scan_tot<<<1, 1024, 0, stream>>>(btot, nb);
    k_scan_add<<<(N + 255) / 256, 256, 0, stream>>>(cnt_i, off, btot, N);
    k_bucket<<<(E + 255) / 256, 256, 0, stream>>>(ei, off, fill, csr, E);

    k_gemm_h<<<(N + 64 * RT - 1) / (64 * RT), 256, 0, stream>>>(x, WgT, att_src, att_dst, h_bf, a_src, a_dst, N);
    k_attn<<<(N + 15) / 16, 256, 0, stream>>>(csr, off, cnt_i, a_src, a_dst, h_bf, bg, hg_bf, N);
    k_gemm2<<<(N + 64 * RT - 1) / (64 * RT), 256, 0, stream>>>(hg_bf, WlT, WrT, hgWl_bf, hgWr_bf, N);
    k_final<<<(N + 15) / 16, 256, 0, stream>>>(csr, off, cnt_i, hgWl_bf, hgWr_bf, bl, out_f, N);
}

// Round 13
// 210.812 us; speedup vs baseline: 1.2068x; 1.0031x over previous
//
#include <hip/hip_runtime.h>
#include <hip/hip_bf16.h>

#define D 128
#define NEG_SLOPE 0.2f
#define SCAN_BS 512
#define RT 4   // row-tiles per wave in the dense GEMM kernels

typedef __attribute__((ext_vector_type(8))) short short8;
typedef __attribute__((ext_vector_type(4))) short short4v;
typedef __attribute__((ext_vector_type(4))) float f32x4;

__device__ __forceinline__ float group_max16(float v) {
#pragma unroll
    for (int m = 8; m >= 1; m >>= 1) v = fmaxf(v, __shfl_xor(v, m));
    return v;
}
__device__ __forceinline__ float group_sum16(float v) {
#pragma unroll
    for (int m = 8; m >= 1; m >>= 1) v += __shfl_xor(v, m);
    return v;
}

__device__ __forceinline__ unsigned short f2bfu(float f) {
    __hip_bfloat16 h = __float2bfloat16(f);
    return *reinterpret_cast<unsigned short*>(&h);
}

__device__ __forceinline__ float bf2f(unsigned short u) {
    return __uint_as_float(((unsigned)u) << 16);
}

__device__ __forceinline__ short8 load_bf8(const float* p) {
    float4 p0 = *(const float4*)p;
    float4 p1 = *(const float4*)(p + 4);
    short8 r;
    r[0] = (short)f2bfu(p0.x); r[1] = (short)f2bfu(p0.y);
    r[2] = (short)f2bfu(p0.z); r[3] = (short)f2bfu(p0.w);
    r[4] = (short)f2bfu(p1.x); r[5] = (short)f2bfu(p1.y);
    r[6] = (short)f2bfu(p1.z); r[7] = (short)f2bfu(p1.w);
    return r;
}

// transpose + convert the three 128x128 weight mats to bf16 (WT[n][k] = W[k][n])
__global__ void k_wt(const float* __restrict__ Wg, const float* __restrict__ Wl,
                     const float* __restrict__ Wr, short* __restrict__ WgT,
                     short* __restrict__ WlT, short* __restrict__ WrT) {
    int i = blockIdx.x * blockDim.x + threadIdx.x;
    int m = i >> 14;
    int r = (i >> 7) & 127;
    int c = i & 127;
    const float* src = (m == 0) ? Wg : (m == 1) ? Wl : Wr;
    short* dst = (m == 0) ? WgT : (m == 1) ? WlT : WrT;
    dst[r * D + c] = (short)f2bfu(src[c * D + r]);
}

// ---- CSR build ----
__global__ void k_hist(const int* __restrict__ ei, int* __restrict__ cnt, int E) {
    int i = blockIdx.x * blockDim.x + threadIdx.x;
    if (i < E) atomicAdd(&cnt[ei[E + i]], 1);
}

__global__ void k_scan_block(const int* __restrict__ cnt, int* __restrict__ incl,
                             int* __restrict__ btot, int N) {
    __shared__ int s[SCAN_BS];
    int t = threadIdx.x, i = blockIdx.x * SCAN_BS + t;
    int v = (i < N) ? cnt[i] : 0;
    s[t] = v;
    __syncthreads();
    for (int d = 1; d < SCAN_BS; d <<= 1) {
        int u = (t >= d) ? s[t - d] : 0;
        __syncthreads();
        s[t] += u;
        __syncthreads();
    }
    if (i < N) incl[i] = s[t];
    if (t == SCAN_BS - 1) btot[blockIdx.x] = s[t];
}

__global__ void k_scan_tot(int* __restrict__ btot, int nb) {
    __shared__ int s[1024];
    int t = threadIdx.x;
    int v = (t < nb) ? btot[t] : 0;
    s[t] = v;
    __syncthreads();
    for (int d = 1; d < 1024; d <<= 1) {
        int u = (t >= d) ? s[t - d] : 0;
        __syncthreads();
        s[t] += u;
        __syncthreads();
    }
    if (t < nb) btot[t] = s[t] - v;
}

__global__ void k_scan_add(const int* __restrict__ cnt, int* __restrict__ off,
                           const int* __restrict__ btot, int N) {
    int i = blockIdx.x * blockDim.x + threadIdx.x;
    if (i < N) off[i] = off[i] + btot[i / SCAN_BS] - cnt[i];
}

__global__ void k_bucket(const int* __restrict__ ei, const int* __restrict__ off,
                         int* __restrict__ fill, int* __restrict__ csr, int E) {
    int i = blockIdx.x * blockDim.x + threadIdx.x;
    if (i < E) {
        int dt = ei[E + i];
        int p = off[dt] + atomicAdd(&fill[dt], 1);
        csr[p] = ei[i];
    }
}

// ---- K1: h = x @ Wg — LDS-staged swizzled weights + RT row-tiles/wave ----
__global__ void __launch_bounds__(256, 1)
k_gemm_h(const float* __restrict__ x, const short* __restrict__ WgT,
         const float* __restrict__ att_src, const float* __restrict__ att_dst,
         unsigned short* __restrict__ h_bf, float* __restrict__ a_src,
         float* __restrict__ a_dst, int N) {
    __shared__ short lds_w[D * D];   // 32 KB, XOR-swizzled copy of WgT
    const int tid = threadIdx.x;
    // stage WgT -> LDS with byte ^= ((row&7)<<4) swizzle (row = byte>>8)
#pragma unroll
    for (int i = 0; i < 8; ++i) {
        int go = (i * 256 + tid) * 16;            // byte offset, coalesced
        int so = go ^ (((go >> 8) & 7) << 4);
        *(short8*)((char*)lds_w + so) = *(const short8*)((const char*)WgT + go);
    }
    __syncthreads();

    const int lane = tid & 63;
    const int wave = tid >> 6;
    const int lrow = lane & 15, lgrp = lane >> 4;
    const int swz = (lrow & 7) << 4;              // (row&7) == (lrow&7) since f*16 ≡ 0 mod 8
    const int base = blockIdx.x * (64 * RT) + wave * (16 * RT);

    short8 ax[RT][4];
    int rows[RT];
    bool okr[RT];
#pragma unroll
    for (int t = 0; t < RT; ++t) {
        rows[t] = base + t * 16 + lrow;
        okr[t] = (rows[t] < N);
        const float* xr = x + (size_t)rows[t] * D + lgrp * 8;
#pragma unroll
        for (int kt = 0; kt < 4; ++kt) {
            if (okr[t]) ax[t][kt] = load_bf8(xr + kt * 32);
            else { short8 zf; for (int j = 0; j < 8; ++j) zf[j] = 0; ax[t][kt] = zf; }
        }
    }

    float ps[RT], pd[RT];
#pragma unroll
    for (int t = 0; t < RT; ++t) { ps[t] = 0.f; pd[t] = 0.f; }

#pragma unroll
    for (int f = 0; f < 8; ++f) {
        short8 wgf[4];
#pragma unroll
        for (int kt = 0; kt < 4; ++kt) {
            int byte = (f * 16 + lrow) * 256 + kt * 64 + lgrp * 16;
            wgf[kt] = *(const short8*)((const char*)lds_w + (byte ^ swz));
        }
        const int cb = f * 16 + lgrp * 4;
        float as[4], adv[4];
#pragma unroll
        for (int j = 0; j < 4; ++j) { as[j] = att_src[cb + j]; adv[j] = att_dst[cb + j]; }
#pragma unroll
        for (int t = 0; t < RT; ++t) {
            f32x4 a = (f32x4){0.f, 0.f, 0.f, 0.f};
#pragma unroll
            for (int kt = 0; kt < 4; ++kt)
                a = __builtin_amdgcn_mfma_f32_16x16x32_bf16(wgf[kt], ax[t][kt], a, 0, 0, 0);
            short4v hv;
#pragma unroll
            for (int j = 0; j < 4; ++j) {
                float v = a[j];
                hv[j] = (short)f2bfu(v);
                ps[t] += v * as[j];
                pd[t] += v * adv[j];
            }
            if (okr[t]) *(short4v*)(h_bf + (size_t)rows[t] * D + cb) = hv;
        }
    }
#pragma unroll
    for (int t = 0; t < RT; ++t) {
        float s = ps[t], dd = pd[t];
        s += __shfl_xor(s, 16); s += __shfl_xor(s, 32);
        dd += __shfl_xor(dd, 16); dd += __shfl_xor(dd, 32);
        if (lgrp == 0 && okr[t]) { a_src[rows[t]] = s; a_dst[rows[t]] = dd; }
    }
}

// ---- GAT aggregation: 16 lanes per dst node (4 nodes/wave), 4-way MLP unroll ----
__global__ void k_attn(const int* __restrict__ csr, const int* __restrict__ off,
                       const int* __restrict__ cnt, const float* __restrict__ a_src,
                       const float* __restrict__ a_dst, const unsigned short* __restrict__ h_bf,
                       const float* __restrict__ bg, unsigned short* __restrict__ hg_bf, int N) {
    const int lane = threadIdx.x & 63;
    const int l16 = lane & 15, grp = lane >> 4;
    const int gbase = grp << 4;
    const int d = blockIdx.x * 16 + ((threadIdx.x >> 6) << 2) + grp;
    if (d >= N) return;
    const int deg = cnt[d], o = off[d];
    const float ad = a_dst[d];
    float es = a_src[d] + ad;
    es = (es > 0.f) ? es : NEG_SLOPE * es;

    const int fo = l16 * 8;
    short8 hv = *(const short8*)(h_bf + (size_t)d * D + fo);
    float acc[8];
    float inv;

    if (deg <= 16) {
        int sv = 0;
        float e = -INFINITY;
        if (l16 < deg) {
            sv = csr[o + l16];
            float t = a_src[sv] + ad;
            e = (t > 0.f) ? t : NEG_SLOPE * t;
        }
        float mx = fmaxf(group_max16(e), es);
        float p = (l16 < deg) ? expf(e - mx) : 0.f;
        float pself = expf(es - mx);
        inv = 1.f / (group_sum16(p) + pself);
#pragma unroll
        for (int j = 0; j < 8; ++j) acc[j] = pself * bf2f((unsigned short)hv[j]);
        int i = 0;
        for (; i + 4 <= deg; i += 4) {
            int s0 = __shfl(sv, gbase + i);
            int s1 = __shfl(sv, gbase + i + 1);
            int s2 = __shfl(sv, gbase + i + 2);
            int s3 = __shfl(sv, gbase + i + 3);
            float p0 = __shfl(p, gbase + i);
            float p1 = __shfl(p, gbase + i + 1);
            float p2 = __shfl(p, gbase + i + 2);
            float p3 = __shfl(p, gbase + i + 3);
            short8 r0 = *(const short8*)(h_bf + (size_t)s0 * D + fo);
            short8 r1 = *(const short8*)(h_bf + (size_t)s1 * D + fo);
            short8 r2 = *(const short8*)(h_bf + (size_t)s2 * D + fo);
            short8 r3 = *(const short8*)(h_bf + (size_t)s3 * D + fo);
#pragma unroll
            for (int j = 0; j < 8; ++j)
                acc[j] += p0 * bf2f((unsigned short)r0[j]) + p1 * bf2f((unsigned short)r1[j])
                        + p2 * bf2f((unsigned short)r2[j]) + p3 * bf2f((unsigned short)r3[j]);
        }
        for (; i < deg; ++i) {
            int s = __shfl(sv, gbase + i);
            float pi = __shfl(p, gbase + i);
            short8 row = *(const short8*)(h_bf + (size_t)s * D + fo);
#pragma unroll
            for (int j = 0; j < 8; ++j) acc[j] += pi * bf2f((unsigned short)row[j]);
        }
    } else {  // rare fallback
        float m2 = es;
        for (int i = l16; i < deg; i += 16) {
            float t = a_src[csr[o + i]] + ad;
            t = (t > 0.f) ? t : NEG_SLOPE * t;
            m2 = fmaxf(m2, t);
        }
        float mx = group_max16(m2);
        float zp = 0.f;
        for (int i = l16; i < deg; i += 16) {
            float t = a_src[csr[o + i]] + ad;
            t = (t > 0.f) ? t : NEG_SLOPE * t;
            zp += expf(t - mx);
        }
        float pself = expf(es - mx);
        inv = 1.f / (group_sum16(zp) + pself);
#pragma unroll
        for (int j = 0; j < 8; ++j) acc[j] = pself * bf2f((unsigned short)hv[j]);
        for (int i = 0; i < deg; ++i) {
            int s = csr[o + i];
            float t = a_src[s] + ad;
            t = (t > 0.f) ? t : NEG_SLOPE * t;
            float pi = expf(t - mx);
            short8 row = *(const short8*)(h_bf + (size_t)s * D + fo);
#pragma unroll
            for (int j = 0; j < 8; ++j) acc[j] += pi * bf2f((unsigned short)row[j]);
        }
    }
    short8 r;
#pragma unroll
    for (int j = 0; j < 8; ++j) r[j] = (short)f2bfu(acc[j] * inv + bg[fo + j]);
    *(short8*)(hg_bf + (size_t)d * D + fo) = r;
}

// ---- K3: hgWl = bf16(hg@Wl); hgWr = bf16(hg@Wr) — RT row-tiles/wave, weight reuse ----
__global__ void k_gemm2(const unsigned short* __restrict__ hg_bf,
                        const short* __restrict__ WlT, const short* __restrict__ WrT,
                        unsigned short* __restrict__ hgWl_bf,
                        unsigned short* __restrict__ hgWr_bf, int N) {
    const int lane = threadIdx.x & 63;
    const int wave = threadIdx.x >> 6;
    const int lrow = lane & 15, lgrp = lane >> 4;
    const int base = blockIdx.x * (64 * RT) + wave * (16 * RT);

    short8 ah[RT][4];
    int rows[RT];
    bool okr[RT];
#pragma unroll
    for (int t = 0; t < RT; ++t) {
        rows[t] = base + t * 16 + lrow;
        okr[t] = (rows[t] < N);
        const unsigned short* hp = hg_bf + (size_t)rows[t] * D + lgrp * 8;
#pragma unroll
        for (int kt = 0; kt < 4; ++kt) {
            if (okr[t]) ah[t][kt] = *(const short8*)(hp + kt * 32);
            else { short8 zf; for (int j = 0; j < 8; ++j) zf[j] = 0; ah[t][kt] = zf; }
        }
    }

#pragma unroll
    for (int f = 0; f < 8; ++f) {
        const short* wl = WlT + ((f * 16 + lrow) * D + lgrp * 8);
        const short* wr = WrT + ((f * 16 + lrow) * D + lgrp * 8);
        short8 wlf[4], wrf[4];
#pragma unroll
        for (int kt = 0; kt < 4; ++kt) {
            wlf[kt] = *(const short8*)(wl + kt * 32);
            wrf[kt] = *(const short8*)(wr + kt * 32);
        }
        const int cb = f * 16 + lgrp * 4;
#pragma unroll
        for (int t = 0; t < RT; ++t) {
            f32x4 aL = (f32x4){0.f, 0.f, 0.f, 0.f};
            f32x4 aR = (f32x4){0.f, 0.f, 0.f, 0.f};
#pragma unroll
            for (int kt = 0; kt < 4; ++kt) {
                aL = __builtin_amdgcn_mfma_f32_16x16x32_bf16(wlf[kt], ah[t][kt], aL, 0, 0, 0);
                aR = __builtin_amdgcn_mfma_f32_16x16x32_bf16(wrf[kt], ah[t][kt], aR, 0, 0, 0);
            }
            if (okr[t]) {
                short4v vl, vr;
#pragma unroll
                for (int j = 0; j < 4; ++j) {
                    vl[j] = (short)f2bfu(aL[j]);
                    vr[j] = (short)f2bfu(aR[j]);
                }
                *(short4v*)(hgWl_bf + (size_t)rows[t] * D + cb) = vl;
                *(short4v*)(hgWr_bf + (size_t)rows[t] * D + cb) = vr;
            }
        }
    }
}

// ---- K4: out = normalize(mean-gather(hgWl) + hgWr + bl) — pure gather ----
__global__ void k_final(const int* __restrict__ csr, const int* __restrict__ off,
                        const int* __restrict__ cnt, const unsigned short* __restrict__ hgWl_bf,
                        const unsigned short* __restrict__ hgWr_bf, const float* __restrict__ bl,
                        float* __restrict__ out, int N) {
    const int lane = threadIdx.x & 63;
    const int l16 = lane & 15, grp = lane >> 4;
    const int gbase = grp << 4;
    const int d = blockIdx.x * 16 + ((threadIdx.x >> 6) << 2) + grp;
    if (d >= N) return;
    const int deg = cnt[d], o = off[d];
    const int fo = l16 * 8;

    short8 wrow = *(const short8*)(hgWr_bf + (size_t)d * D + fo);
    float4 b0 = *(const float4*)(bl + fo);
    float4 b1 = *(const float4*)(bl + fo + 4);

    float acc[8];
#pragma unroll
    for (int j = 0; j < 8; ++j) acc[j] = 0.f;

    if (deg <= 16) {
        int sv = 0;
        if (l16 < deg) sv = csr[o + l16];
        int i = 0;
        for (; i + 4 <= deg; i += 4) {
            int s0 = __shfl(sv, gbase + i);
            int s1 = __shfl(sv, gbase + i + 1);
            int s2 = __shfl(sv, gbase + i + 2);
            int s3 = __shfl(sv, gbase + i + 3);
            short8 r0 = *(const short8*)(hgWl_bf + (size_t)s0 * D + fo);
            short8 r1 = *(const short8*)(hgWl_bf + (size_t)s1 * D + fo);
            short8 r2 = *(const short8*)(hgWl_bf + (size_t)s2 * D + fo);
            short8 r3 = *(const short8*)(hgWl_bf + (size_t)s3 * D + fo);
#pragma unroll
            for (int j = 0; j < 8; ++j)
                acc[j] += bf2f((unsigned short)r0[j]) + bf2f((unsigned short)r1[j])
                        + bf2f((unsigned short)r2[j]) + bf2f((unsigned short)r3[j]);
        }
        for (; i < deg; ++i) {
            int s = __shfl(sv, gbase + i);
            short8 row = *(const short8*)(hgWl_bf + (size_t)s * D + fo);
#pragma unroll
            for (int j = 0; j < 8; ++j) acc[j] += bf2f((unsigned short)row[j]);
        }
    } else {
        for (int i = 0; i < deg; ++i) {
            int s = csr[o + i];
            short8 row = *(const short8*)(hgWl_bf + (size_t)s * D + fo);
#pragma unroll
            for (int j = 0; j < 8; ++j) acc[j] += bf2f((unsigned short)row[j]);
        }
    }

    const float minv = 1.f / fmaxf((float)deg, 1.f);
    float v[8];
    v[0] = acc[0] * minv + bf2f((unsigned short)wrow[0]) + b0.x;
    v[1] = acc[1] * minv + bf2f((unsigned short)wrow[1]) + b0.y;
    v[2] = acc[2] * minv + bf2f((unsigned short)wrow[2]) + b0.z;
    v[3] = acc[3] * minv + bf2f((unsigned short)wrow[3]) + b0.w;
    v[4] = acc[4] * minv + bf2f((unsigned short)wrow[4]) + b1.x;
    v[5] = acc[5] * minv + bf2f((unsigned short)wrow[5]) + b1.y;
    v[6] = acc[6] * minv + bf2f((unsigned short)wrow[6]) + b1.z;
    v[7] = acc[7] * minv + bf2f((unsigned short)wrow[7]) + b1.w;
    float ss = 0.f;
#pragma unroll
    for (int j = 0; j < 8; ++j) ss += v[j] * v[j];
    ss = group_sum16(ss);
    float sc = 1.f / fmaxf(sqrtf(ss), 1e-12f);
    float* orow = out + (size_t)d * D + fo;
    float4 w0 = {v[0] * sc, v[1] * sc, v[2] * sc, v[3] * sc};
    float4 w1 = {v[4] * sc, v[5] * sc, v[6] * sc, v[7] * sc};
    *(float4*)orow = w0;
    *(float4*)(orow + 4) = w1;
}

extern "C" void kernel_launch(void* const* d_in, const int* in_sizes, int n_in,
                              void* d_out, int out_size, void* d_ws, size_t ws_size,
                              hipStream_t stream) {
    const float* x       = (const float*)d_in[0];
    const int*   ei      = (const int*)d_in[1];
    const float* Wg      = (const float*)d_in[2];
    const float* att_src = (const float*)d_in[3];
    const float* att_dst = (const float*)d_in[4];
    const float* bg      = (const float*)d_in[5];
    const float* Wl      = (const float*)d_in[6];
    const float* bl      = (const float*)d_in[7];
    const float* Wr      = (const float*)d_in[8];
    const int N = in_sizes[0] / D;
    const int E = in_sizes[1] / 2;

    char* w = (char*)d_ws;
    unsigned short* h_bf    = (unsigned short*)w;  w += (size_t)N * D * 2;
    unsigned short* hg_bf   = (unsigned short*)w;  w += (size_t)N * D * 2;
    unsigned short* hgWl_bf = (unsigned short*)w;  w += (size_t)N * D * 2;
    unsigned short* hgWr_bf = (unsigned short*)w;  w += (size_t)N * D * 2;
    float* a_src = (float*)w;  w += (size_t)N * 4;
    float* a_dst = (float*)w;  w += (size_t)N * 4;
    int*   cnt_i = (int*)w;    w += (size_t)N * 4;
    int*   off   = (int*)w;    w += (size_t)N * 4;
    int*   fill  = (int*)w;    w += (size_t)N * 4;
    int*   btot  = (int*)w;    w += 1024 * 4;
    int*   csr   = (int*)w;    w += (size_t)E * 4;
    short* WgT   = (short*)w;  w += (size_t)D * D * 2;
    short* WlT   = (short*)w;  w += (size_t)D * D * 2;
    short* WrT   = (short*)w;  w += (size_t)D * D * 2;
    float* out_f = (float*)d_out;

    (void)hipMemsetAsync(cnt_i, 0, (size_t)N * 4, stream);
    (void)hipMemsetAsync(fill, 0, (size_t)N * 4, stream);

    const int nb = (N + SCAN_BS - 1) / SCAN_BS;

    k_wt<<<(3 * D * D) / 256, 256, 0, stream>>>(Wg, Wl, Wr, WgT, WlT, WrT);
    k_hist<<<(E + 255) / 256, 256, 0, stream>>>(ei, cnt_i, E);
    k_scan_block<<<nb, SCAN_BS, 0, stream>>>(cnt_i, off, btot, N);
    k_scan_tot<<<1, 1024, 0, stream>>>(btot, nb);
    k_scan_add<<<(N + 255) / 256, 256, 0, stream>>>(cnt_i, off, btot, N);
    k_bucket<<<(E + 255) / 256, 256, 0, stream>>>(ei, off, fill, csr, E);

    k_gemm_h<<<(N + 64 * RT - 1) / (64 * RT), 256, 0, stream>>>(x, WgT, att_src, att_dst, h_bf, a_src, a_dst, N);
    k_attn<<<(N + 15) / 16, 256, 0, stream>>>(csr, off, cnt_i, a_src, a_dst, h_bf, bg, hg_bf, N);
    k_gemm2<<<(N + 64 * RT - 1) / (64 * RT), 256, 0, stream>>>(hg_bf, WlT, WrT, hgWl_bf, hgWr_bf, N);
    k_final<<<(N + 15) / 16, 256, 0, stream>>>(csr, off, cnt_i, hgWl_bf, hgWr_bf, bl, out_f, N);
}

// Round 14
// 205.373 us; speedup vs baseline: 1.2387x; 1.0265x over previous
//
#include <hip/hip_runtime.h>
#include <hip/hip_bf16.h>

#define D 128
#define NEG_SLOPE 0.2f
#define SCAN_BS 512
#define RT 4    // row-tiles per wave in k_gemm2
#define RTH 2   // row-tiles per wave in k_gemm_h (spill + TLP: see r13 post-mortem)

typedef __attribute__((ext_vector_type(8))) short short8;
typedef __attribute__((ext_vector_type(4))) short short4v;
typedef __attribute__((ext_vector_type(4))) float f32x4;

__device__ __forceinline__ float group_max16(float v) {
#pragma unroll
    for (int m = 8; m >= 1; m >>= 1) v = fmaxf(v, __shfl_xor(v, m));
    return v;
}
__device__ __forceinline__ float group_sum16(float v) {
#pragma unroll
    for (int m = 8; m >= 1; m >>= 1) v += __shfl_xor(v, m);
    return v;
}

__device__ __forceinline__ unsigned short f2bfu(float f) {
    __hip_bfloat16 h = __float2bfloat16(f);
    return *reinterpret_cast<unsigned short*>(&h);
}

__device__ __forceinline__ float bf2f(unsigned short u) {
    return __uint_as_float(((unsigned)u) << 16);
}

__device__ __forceinline__ short8 load_bf8(const float* p) {
    float4 p0 = *(const float4*)p;
    float4 p1 = *(const float4*)(p + 4);
    short8 r;
    r[0] = (short)f2bfu(p0.x); r[1] = (short)f2bfu(p0.y);
    r[2] = (short)f2bfu(p0.z); r[3] = (short)f2bfu(p0.w);
    r[4] = (short)f2bfu(p1.x); r[5] = (short)f2bfu(p1.y);
    r[6] = (short)f2bfu(p1.z); r[7] = (short)f2bfu(p1.w);
    return r;
}

// transpose + convert the three 128x128 weight mats to bf16 (WT[n][k] = W[k][n])
__global__ void k_wt(const float* __restrict__ Wg, const float* __restrict__ Wl,
                     const float* __restrict__ Wr, short* __restrict__ WgT,
                     short* __restrict__ WlT, short* __restrict__ WrT) {
    int i = blockIdx.x * blockDim.x + threadIdx.x;
    int m = i >> 14;
    int r = (i >> 7) & 127;
    int c = i & 127;
    const float* src = (m == 0) ? Wg : (m == 1) ? Wl : Wr;
    short* dst = (m == 0) ? WgT : (m == 1) ? WlT : WrT;
    dst[r * D + c] = (short)f2bfu(src[c * D + r]);
}

// ---- CSR build ----
__global__ void k_hist(const int* __restrict__ ei, int* __restrict__ cnt, int E) {
    int i = blockIdx.x * blockDim.x + threadIdx.x;
    if (i < E) atomicAdd(&cnt[ei[E + i]], 1);
}

__global__ void k_scan_block(const int* __restrict__ cnt, int* __restrict__ incl,
                             int* __restrict__ btot, int N) {
    __shared__ int s[SCAN_BS];
    int t = threadIdx.x, i = blockIdx.x * SCAN_BS + t;
    int v = (i < N) ? cnt[i] : 0;
    s[t] = v;
    __syncthreads();
    for (int d = 1; d < SCAN_BS; d <<= 1) {
        int u = (t >= d) ? s[t - d] : 0;
        __syncthreads();
        s[t] += u;
        __syncthreads();
    }
    if (i < N) incl[i] = s[t];
    if (t == SCAN_BS - 1) btot[blockIdx.x] = s[t];
}

__global__ void k_scan_tot(int* __restrict__ btot, int nb) {
    __shared__ int s[1024];
    int t = threadIdx.x;
    int v = (t < nb) ? btot[t] : 0;
    s[t] = v;
    __syncthreads();
    for (int d = 1; d < 1024; d <<= 1) {
        int u = (t >= d) ? s[t - d] : 0;
        __syncthreads();
        s[t] += u;
        __syncthreads();
    }
    if (t < nb) btot[t] = s[t] - v;
}

__global__ void k_scan_add(const int* __restrict__ cnt, int* __restrict__ off,
                           const int* __restrict__ btot, int N) {
    int i = blockIdx.x * blockDim.x + threadIdx.x;
    if (i < N) off[i] = off[i] + btot[i / SCAN_BS] - cnt[i];
}

__global__ void k_bucket(const int* __restrict__ ei, const int* __restrict__ off,
                         int* __restrict__ fill, int* __restrict__ csr, int E) {
    int i = blockIdx.x * blockDim.x + threadIdx.x;
    if (i < E) {
        int dt = ei[E + i];
        int p = off[dt] + atomicAdd(&fill[dt], 1);
        csr[p] = ei[i];
    }
}

// ---- K1: h = x @ Wg — LDS-staged swizzled weights + RTH row-tiles/wave ----
__global__ void __launch_bounds__(256, 1)
k_gemm_h(const float* __restrict__ x, const short* __restrict__ WgT,
         const float* __restrict__ att_src, const float* __restrict__ att_dst,
         unsigned short* __restrict__ h_bf, float* __restrict__ a_src,
         float* __restrict__ a_dst, int N) {
    __shared__ short lds_w[D * D];   // 32 KB, XOR-swizzled copy of WgT
    const int tid = threadIdx.x;
#pragma unroll
    for (int i = 0; i < 8; ++i) {
        int go = (i * 256 + tid) * 16;            // byte offset, coalesced
        int so = go ^ (((go >> 8) & 7) << 4);
        *(short8*)((char*)lds_w + so) = *(const short8*)((const char*)WgT + go);
    }
    __syncthreads();

    const int lane = tid & 63;
    const int wave = tid >> 6;
    const int lrow = lane & 15, lgrp = lane >> 4;
    const int swz = (lrow & 7) << 4;
    const int base = blockIdx.x * (64 * RTH) + wave * (16 * RTH);

    short8 ax[RTH][4];
    int rows[RTH];
    bool okr[RTH];
#pragma unroll
    for (int t = 0; t < RTH; ++t) {
        rows[t] = base + t * 16 + lrow;
        okr[t] = (rows[t] < N);
        const float* xr = x + (size_t)rows[t] * D + lgrp * 8;
#pragma unroll
        for (int kt = 0; kt < 4; ++kt) {
            if (okr[t]) ax[t][kt] = load_bf8(xr + kt * 32);
            else { short8 zf; for (int j = 0; j < 8; ++j) zf[j] = 0; ax[t][kt] = zf; }
        }
    }

    float ps[RTH], pd[RTH];
#pragma unroll
    for (int t = 0; t < RTH; ++t) { ps[t] = 0.f; pd[t] = 0.f; }

#pragma unroll
    for (int f = 0; f < 8; ++f) {
        short8 wgf[4];
#pragma unroll
        for (int kt = 0; kt < 4; ++kt) {
            int byte = (f * 16 + lrow) * 256 + kt * 64 + lgrp * 16;
            wgf[kt] = *(const short8*)((const char*)lds_w + (byte ^ swz));
        }
        const int cb = f * 16 + lgrp * 4;
        float as[4], adv[4];
#pragma unroll
        for (int j = 0; j < 4; ++j) { as[j] = att_src[cb + j]; adv[j] = att_dst[cb + j]; }
#pragma unroll
        for (int t = 0; t < RTH; ++t) {
            f32x4 a = (f32x4){0.f, 0.f, 0.f, 0.f};
#pragma unroll
            for (int kt = 0; kt < 4; ++kt)
                a = __builtin_amdgcn_mfma_f32_16x16x32_bf16(wgf[kt], ax[t][kt], a, 0, 0, 0);
            short4v hv;
#pragma unroll
            for (int j = 0; j < 4; ++j) {
                float v = a[j];
                hv[j] = (short)f2bfu(v);
                ps[t] += v * as[j];
                pd[t] += v * adv[j];
            }
            if (okr[t]) *(short4v*)(h_bf + (size_t)rows[t] * D + cb) = hv;
        }
    }
#pragma unroll
    for (int t = 0; t < RTH; ++t) {
        float s = ps[t], dd = pd[t];
        s += __shfl_xor(s, 16); s += __shfl_xor(s, 32);
        dd += __shfl_xor(dd, 16); dd += __shfl_xor(dd, 32);
        if (lgrp == 0 && okr[t]) { a_src[rows[t]] = s; a_dst[rows[t]] = dd; }
    }
}

// ---- GAT aggregation: 16 lanes per dst node (4 nodes/wave), 4-way MLP unroll ----
__global__ void k_attn(const int* __restrict__ csr, const int* __restrict__ off,
                       const int* __restrict__ cnt, const float* __restrict__ a_src,
                       const float* __restrict__ a_dst, const unsigned short* __restrict__ h_bf,
                       const float* __restrict__ bg, unsigned short* __restrict__ hg_bf, int N) {
    const int lane = threadIdx.x & 63;
    const int l16 = lane & 15, grp = lane >> 4;
    const int gbase = grp << 4;
    const int d = blockIdx.x * 16 + ((threadIdx.x >> 6) << 2) + grp;
    if (d >= N) return;
    const int deg = cnt[d], o = off[d];
    const float ad = a_dst[d];
    float es = a_src[d] + ad;
    es = (es > 0.f) ? es : NEG_SLOPE * es;

    const int fo = l16 * 8;
    short8 hv = *(const short8*)(h_bf + (size_t)d * D + fo);
    float acc[8];
    float inv;

    if (deg <= 16) {
        int sv = 0;
        float e = -INFINITY;
        if (l16 < deg) {
            sv = csr[o + l16];
            float t = a_src[sv] + ad;
            e = (t > 0.f) ? t : NEG_SLOPE * t;
        }
        float mx = fmaxf(group_max16(e), es);
        float p = (l16 < deg) ? expf(e - mx) : 0.f;
        float pself = expf(es - mx);
        inv = 1.f / (group_sum16(p) + pself);
#pragma unroll
        for (int j = 0; j < 8; ++j) acc[j] = pself * bf2f((unsigned short)hv[j]);
        int i = 0;
        for (; i + 4 <= deg; i += 4) {
            int s0 = __shfl(sv, gbase + i);
            int s1 = __shfl(sv, gbase + i + 1);
            int s2 = __shfl(sv, gbase + i + 2);
            int s3 = __shfl(sv, gbase + i + 3);
            float p0 = __shfl(p, gbase + i);
            float p1 = __shfl(p, gbase + i + 1);
            float p2 = __shfl(p, gbase + i + 2);
            float p3 = __shfl(p, gbase + i + 3);
            short8 r0 = *(const short8*)(h_bf + (size_t)s0 * D + fo);
            short8 r1 = *(const short8*)(h_bf + (size_t)s1 * D + fo);
            short8 r2 = *(const short8*)(h_bf + (size_t)s2 * D + fo);
            short8 r3 = *(const short8*)(h_bf + (size_t)s3 * D + fo);
#pragma unroll
            for (int j = 0; j < 8; ++j)
                acc[j] += p0 * bf2f((unsigned short)r0[j]) + p1 * bf2f((unsigned short)r1[j])
                        + p2 * bf2f((unsigned short)r2[j]) + p3 * bf2f((unsigned short)r3[j]);
        }
        for (; i < deg; ++i) {
            int s = __shfl(sv, gbase + i);
            float pi = __shfl(p, gbase + i);
            short8 row = *(const short8*)(h_bf + (size_t)s * D + fo);
#pragma unroll
            for (int j = 0; j < 8; ++j) acc[j] += pi * bf2f((unsigned short)row[j]);
        }
    } else {  // rare fallback
        float m2 = es;
        for (int i = l16; i < deg; i += 16) {
            float t = a_src[csr[o + i]] + ad;
            t = (t > 0.f) ? t : NEG_SLOPE * t;
            m2 = fmaxf(m2, t);
        }
        float mx = group_max16(m2);
        float zp = 0.f;
        for (int i = l16; i < deg; i += 16) {
            float t = a_src[csr[o + i]] + ad;
            t = (t > 0.f) ? t : NEG_SLOPE * t;
            zp += expf(t - mx);
        }
        float pself = expf(es - mx);
        inv = 1.f / (group_sum16(zp) + pself);
#pragma unroll
        for (int j = 0; j < 8; ++j) acc[j] = pself * bf2f((unsigned short)hv[j]);
        for (int i = 0; i < deg; ++i) {
            int s = csr[o + i];
            float t = a_src[s] + ad;
            t = (t > 0.f) ? t : NEG_SLOPE * t;
            float pi = expf(t - mx);
            short8 row = *(const short8*)(h_bf + (size_t)s * D + fo);
#pragma unroll
            for (int j = 0; j < 8; ++j) acc[j] += pi * bf2f((unsigned short)row[j]);
        }
    }
    short8 r;
#pragma unroll
    for (int j = 0; j < 8; ++j) r[j] = (short)f2bfu(acc[j] * inv + bg[fo + j]);
    *(short8*)(hg_bf + (size_t)d * D + fo) = r;
}

// ---- K3: hgWl = bf16(hg@Wl); hgWr = bf16(hg@Wr) — RT row-tiles/wave, weight reuse ----
__global__ void k_gemm2(const unsigned short* __restrict__ hg_bf,
                        const short* __restrict__ WlT, const short* __restrict__ WrT,
                        unsigned short* __restrict__ hgWl_bf,
                        unsigned short* __restrict__ hgWr_bf, int N) {
    const int lane = threadIdx.x & 63;
    const int wave = threadIdx.x >> 6;
    const int lrow = lane & 15, lgrp = lane >> 4;
    const int base = blockIdx.x * (64 * RT) + wave * (16 * RT);

    short8 ah[RT][4];
    int rows[RT];
    bool okr[RT];
#pragma unroll
    for (int t = 0; t < RT; ++t) {
        rows[t] = base + t * 16 + lrow;
        okr[t] = (rows[t] < N);
        const unsigned short* hp = hg_bf + (size_t)rows[t] * D + lgrp * 8;
#pragma unroll
        for (int kt = 0; kt < 4; ++kt) {
            if (okr[t]) ah[t][kt] = *(const short8*)(hp + kt * 32);
            else { short8 zf; for (int j = 0; j < 8; ++j) zf[j] = 0; ah[t][kt] = zf; }
        }
    }

#pragma unroll
    for (int f = 0; f < 8; ++f) {
        const short* wl = WlT + ((f * 16 + lrow) * D + lgrp * 8);
        const short* wr = WrT + ((f * 16 + lrow) * D + lgrp * 8);
        short8 wlf[4], wrf[4];
#pragma unroll
        for (int kt = 0; kt < 4; ++kt) {
            wlf[kt] = *(const short8*)(wl + kt * 32);
            wrf[kt] = *(const short8*)(wr + kt * 32);
        }
        const int cb = f * 16 + lgrp * 4;
#pragma unroll
        for (int t = 0; t < RT; ++t) {
            f32x4 aL = (f32x4){0.f, 0.f, 0.f, 0.f};
            f32x4 aR = (f32x4){0.f, 0.f, 0.f, 0.f};
#pragma unroll
            for (int kt = 0; kt < 4; ++kt) {
                aL = __builtin_amdgcn_mfma_f32_16x16x32_bf16(wlf[kt], ah[t][kt], aL, 0, 0, 0);
                aR = __builtin_amdgcn_mfma_f32_16x16x32_bf16(wrf[kt], ah[t][kt], aR, 0, 0, 0);
            }
            if (okr[t]) {
                short4v vl, vr;
#pragma unroll
                for (int j = 0; j < 4; ++j) {
                    vl[j] = (short)f2bfu(aL[j]);
                    vr[j] = (short)f2bfu(aR[j]);
                }
                *(short4v*)(hgWl_bf + (size_t)rows[t] * D + cb) = vl;
                *(short4v*)(hgWr_bf + (size_t)rows[t] * D + cb) = vr;
            }
        }
    }
}

// ---- K4: out = normalize(mean-gather(hgWl) + hgWr + bl) — pure gather ----
__global__ void k_final(const int* __restrict__ csr, const int* __restrict__ off,
                        const int* __restrict__ cnt, const unsigned short* __restrict__ hgWl_bf,
                        const unsigned short* __restrict__ hgWr_bf, const float* __restrict__ bl,
                        float* __restrict__ out, int N) {
    const int lane = threadIdx.x & 63;
    const int l16 = lane & 15, grp = lane >> 4;
    const int gbase = grp << 4;
    const int d = blockIdx.x * 16 + ((threadIdx.x >> 6) << 2) + grp;
    if (d >= N) return;
    const int deg = cnt[d], o = off[d];
    const int fo = l16 * 8;

    short8 wrow = *(const short8*)(hgWr_bf + (size_t)d * D + fo);
    float4 b0 = *(const float4*)(bl + fo);
    float4 b1 = *(const float4*)(bl + fo + 4);

    float acc[8];
#pragma unroll
    for (int j = 0; j < 8; ++j) acc[j] = 0.f;

    if (deg <= 16) {
        int sv = 0;
        if (l16 < deg) sv = csr[o + l16];
        int i = 0;
        for (; i + 4 <= deg; i += 4) {
            int s0 = __shfl(sv, gbase + i);
            int s1 = __shfl(sv, gbase + i + 1);
            int s2 = __shfl(sv, gbase + i + 2);
            int s3 = __shfl(sv, gbase + i + 3);
            short8 r0 = *(const short8*)(hgWl_bf + (size_t)s0 * D + fo);
            short8 r1 = *(const short8*)(hgWl_bf + (size_t)s1 * D + fo);
            short8 r2 = *(const short8*)(hgWl_bf + (size_t)s2 * D + fo);
            short8 r3 = *(const short8*)(hgWl_bf + (size_t)s3 * D + fo);
#pragma unroll
            for (int j = 0; j < 8; ++j)
                acc[j] += bf2f((unsigned short)r0[j]) + bf2f((unsigned short)r1[j])
                        + bf2f((unsigned short)r2[j]) + bf2f((unsigned short)r3[j]);
        }
        for (; i < deg; ++i) {
            int s = __shfl(sv, gbase + i);
            short8 row = *(const short8*)(hgWl_bf + (size_t)s * D + fo);
#pragma unroll
            for (int j = 0; j < 8; ++j) acc[j] += bf2f((unsigned short)row[j]);
        }
    } else {
        for (int i = 0; i < deg; ++i) {
            int s = csr[o + i];
            short8 row = *(const short8*)(hgWl_bf + (size_t)s * D + fo);
#pragma unroll
            for (int j = 0; j < 8; ++j) acc[j] += bf2f((unsigned short)row[j]);
        }
    }

    const float minv = 1.f / fmaxf((float)deg, 1.f);
    float v[8];
    v[0] = acc[0] * minv + bf2f((unsigned short)wrow[0]) + b0.x;
    v[1] = acc[1] * minv + bf2f((unsigned short)wrow[1]) + b0.y;
    v[2] = acc[2] * minv + bf2f((unsigned short)wrow[2]) + b0.z;
    v[3] = acc[3] * minv + bf2f((unsigned short)wrow[3]) + b0.w;
    v[4] = acc[4] * minv + bf2f((unsigned short)wrow[4]) + b1.x;
    v[5] = acc[5] * minv + bf2f((unsigned short)wrow[5]) + b1.y;
    v[6] = acc[6] * minv + bf2f((unsigned short)wrow[6]) + b1.z;
    v[7] = acc[7] * minv + bf2f((unsigned short)wrow[7]) + b1.w;
    float ss = 0.f;
#pragma unroll
    for (int j = 0; j < 8; ++j) ss += v[j] * v[j];
    ss = group_sum16(ss);
    float sc = 1.f / fmaxf(sqrtf(ss), 1e-12f);
    float* orow = out + (size_t)d * D + fo;
    float4 w0 = {v[0] * sc, v[1] * sc, v[2] * sc, v[3] * sc};
    float4 w1 = {v[4] * sc, v[5] * sc, v[6] * sc, v[7] * sc};
    *(float4*)orow = w0;
    *(float4*)(orow + 4) = w1;
}

extern "C" void kernel_launch(void* const* d_in, const int* in_sizes, int n_in,
                              void* d_out, int out_size, void* d_ws, size_t ws_size,
                              hipStream_t stream) {
    const float* x       = (const float*)d_in[0];
    const int*   ei      = (const int*)d_in[1];
    const float* Wg      = (const float*)d_in[2];
    const float* att_src = (const float*)d_in[3];
    const float* att_dst = (const float*)d_in[4];
    const float* bg      = (const float*)d_in[5];
    const float* Wl      = (const float*)d_in[6];
    const float* bl      = (const float*)d_in[7];
    const float* Wr      = (const float*)d_in[8];
    const int N = in_sizes[0] / D;
    const int E = in_sizes[1] / 2;

    char* w = (char*)d_ws;
    unsigned short* h_bf    = (unsigned short*)w;  w += (size_t)N * D * 2;
    unsigned short* hg_bf   = (unsigned short*)w;  w += (size_t)N * D * 2;
    unsigned short* hgWl_bf = (unsigned short*)w;  w += (size_t)N * D * 2;
    unsigned short* hgWr_bf = (unsigned short*)w;  w += (size_t)N * D * 2;
    float* a_src = (float*)w;  w += (size_t)N * 4;
    float* a_dst = (float*)w;  w += (size_t)N * 4;
    int*   cnt_i = (int*)w;    w += (size_t)N * 4;
    int*   off   = (int*)w;    w += (size_t)N * 4;
    int*   fill  = (int*)w;    w += (size_t)N * 4;
    int*   btot  = (int*)w;    w += 1024 * 4;
    int*   csr   = (int*)w;    w += (size_t)E * 4;
    short* WgT   = (short*)w;  w += (size_t)D * D * 2;
    short* WlT   = (short*)w;  w += (size_t)D * D * 2;
    short* WrT   = (short*)w;  w += (size_t)D * D * 2;
    float* out_f = (float*)d_out;

    (void)hipMemsetAsync(cnt_i, 0, (size_t)N * 4, stream);
    (void)hipMemsetAsync(fill, 0, (size_t)N * 4, stream);

    const int nb = (N + SCAN_BS - 1) / SCAN_BS;

    k_wt<<<(3 * D * D) / 256, 256, 0, stream>>>(Wg, Wl, Wr, WgT, WlT, WrT);
    k_hist<<<(E + 255) / 256, 256, 0, stream>>>(ei, cnt_i, E);
    k_scan_block<<<nb, SCAN_BS, 0, stream>>>(cnt_i, off, btot, N);
    k_scan_tot<<<1, 1024, 0, stream>>>(btot, nb);
    k_scan_add<<<(N + 255) / 256, 256, 0, stream>>>(cnt_i, off, btot, N);
    k_bucket<<<(E + 255) / 256, 256, 0, stream>>>(ei, off, fill, csr, E);

    k_gemm_h<<<(N + 64 * RTH - 1) / (64 * RTH), 256, 0, stream>>>(x, WgT, att_src, att_dst, h_bf, a_src, a_dst, N);
    k_attn<<<(N + 15) / 16, 256, 0, stream>>>(csr, off, cnt_i, a_src, a_dst, h_bf, bg, hg_bf, N);
    k_gemm2<<<(N + 64 * RT - 1) / (64 * RT), 256, 0, stream>>>(hg_bf, WlT, WrT, hgWl_bf, hgWr_bf, N);
    k_final<<<(N + 15) / 16, 256, 0, stream>>>(csr, off, cnt_i, hgWl_bf, hgWr_bf, bl, out_f, N);
}